// Round 5
// baseline (345.130 us; speedup 1.0000x reference)
//
#include <hip/hip_runtime.h>

typedef float  f32x4  __attribute__((ext_vector_type(4)));
typedef short  bf16x8 __attribute__((ext_vector_type(8)));
typedef unsigned short u16;

constexpr int B_ = 4;
constexpr int C_ = 128;
constexpr int N_ = 4096;
constexpr int G_ = 8;
constexpr int CperG = 16;
constexpr float EPS_ = 1e-5f;
constexpr float SCALE_ = 0.08838834764831845f;  // 1/sqrt(C)

__device__ inline u16 f2bf(float f) {
    union { float f; unsigned u; } v; v.f = f;
    unsigned r = v.u + 0x7fffu + ((v.u >> 16) & 1u);  // RNE
    return (u16)(r >> 16);
}
__device__ inline unsigned pk2(float a, float b) {
    return (unsigned)f2bf(a) | ((unsigned)f2bf(b) << 16);
}
// load 8 consecutive fp32, pack to bf16x8 (inline weight conversion)
__device__ inline bf16x8 ldw8(const float* p) {
    float4 a = *(const float4*)p;
    float4 b = *(const float4*)(p + 4);
    union { bf16x8 h; unsigned u[4]; } r;
    r.u[0] = pk2(a.x, a.y); r.u[1] = pk2(a.z, a.w);
    r.u[2] = pk2(b.x, b.y); r.u[3] = pk2(b.z, b.w);
    return r.h;
}

// ---------------- 1. GroupNorm partial sums (atomic) ----------------
__global__ __launch_bounds__(256) void prep_kernel(const float* __restrict__ x,
                                                   float* __restrict__ stats) {
    __shared__ float rs[4], rss[4];
    int bg = blockIdx.x >> 3, chunk = blockIdx.x & 7;
    const float4* xp = (const float4*)(x + (size_t)bg * (CperG * N_)) + chunk * 2048;
    float s = 0.f, ss = 0.f;
    for (int i = threadIdx.x; i < 2048; i += 256) {
        float4 v = xp[i];
        s  += v.x + v.y + v.z + v.w;
        ss += v.x*v.x + v.y*v.y + v.z*v.z + v.w*v.w;
    }
    #pragma unroll
    for (int off = 32; off > 0; off >>= 1) {
        s  += __shfl_down(s, off);
        ss += __shfl_down(ss, off);
    }
    int wv = threadIdx.x >> 6, ln = threadIdx.x & 63;
    if (ln == 0) { rs[wv] = s; rss[wv] = ss; }
    __syncthreads();
    if (threadIdx.x == 0) {
        atomicAdd(&stats[bg*2],     rs[0] + rs[1] + rs[2] + rs[3]);
        atomicAdd(&stats[bg*2 + 1], rss[0] + rss[1] + rss[2] + rss[3]);
    }
}

// ---------------- 2. QKV via MFMA (fused GN, inline W->bf16) -> bf16 --------
// Qt[b][n][c]=(q+qb)*SCALE ; Kt[b][n][c]=k+qb ; Vb[b][c][n]=v+qb.
// Block: 32-pixel tile, 4 waves. Wave: p2=w>>1 pixel half, h2=w&1 o-half.
constexpr int HS = 136;

__global__ __launch_bounds__(256) void qkv_kernel(const float* __restrict__ x,
                                                  const float* __restrict__ stats,
                                                  const float* __restrict__ nw,
                                                  const float* __restrict__ nb,
                                                  const float* __restrict__ qw,
                                                  const float* __restrict__ qb,
                                                  u16* __restrict__ Qt,
                                                  u16* __restrict__ Kt,
                                                  u16* __restrict__ Vb) {
    int n0 = (blockIdx.x & 127) * 32;
    int b  = blockIdx.x >> 7;
    __shared__ u16 hs[32 * HS];
    int t = threadIdx.x;
    const float invM = 1.f / (float)(CperG * N_);
    #pragma unroll
    for (int r = 0; r < 4; ++r) {
        int idx = t + (r << 8);
        int c = idx >> 3, n4 = idx & 7;
        int g = c >> 4;
        float S = stats[(b*G_ + g)*2], SS = stats[(b*G_ + g)*2 + 1];
        float mean = S * invM;
        float rstd = rsqrtf(SS * invM - mean*mean + EPS_);
        float wgt = nw[c] * rstd;
        float bia = nb[c] - mean * wgt;
        float4 xv = *(const float4*)(x + ((size_t)(b*C_ + c))*N_ + n0 + n4*4);
        int base = (n4*4) * HS + c;
        hs[base         ] = f2bf(xv.x*wgt + bia);
        hs[base +     HS] = f2bf(xv.y*wgt + bia);
        hs[base + 2 * HS] = f2bf(xv.z*wgt + bia);
        hs[base + 3 * HS] = f2bf(xv.w*wgt + bia);
    }
    __syncthreads();
    int w = t >> 6, lane = t & 63, lo = lane & 15, hi = lane >> 4;
    int p2 = w >> 1, h2 = w & 1;
    bf16x8 hf[4];
    #pragma unroll
    for (int ch = 0; ch < 4; ++ch)
        hf[ch] = *(const bf16x8*)(hs + (16*p2 + lo)*HS + 32*ch + 8*hi);

    // Q (h2=0) or K (h2=1): 8 o-tiles. A=W [o][c], B=h -> D[o][pix]
    #pragma unroll
    for (int ot = 0; ot < 8; ++ot) {
        int ob = (h2*8 + ot) * 16;
        f32x4 acc = (f32x4){0.f, 0.f, 0.f, 0.f};
        #pragma unroll
        for (int ch = 0; ch < 4; ++ch) {
            bf16x8 wf = ldw8(qw + (size_t)(ob + lo)*C_ + 32*ch + 8*hi);
            acc = __builtin_amdgcn_mfma_f32_16x16x32_bf16(wf, hf[ch], acc, 0, 0, 0);
        }
        float4 bv = *(const float4*)(qb + ob + 4*hi);
        int n = n0 + 16*p2 + lo;
        ushort4 o4;
        if (h2 == 0) {
            o4.x = f2bf((acc[0] + bv.x) * SCALE_);
            o4.y = f2bf((acc[1] + bv.y) * SCALE_);
            o4.z = f2bf((acc[2] + bv.z) * SCALE_);
            o4.w = f2bf((acc[3] + bv.w) * SCALE_);
            *(ushort4*)(Qt + ((size_t)b*N_ + n)*C_ + ob + 4*hi) = o4;
        } else {
            o4.x = f2bf(acc[0] + bv.x);
            o4.y = f2bf(acc[1] + bv.y);
            o4.z = f2bf(acc[2] + bv.z);
            o4.w = f2bf(acc[3] + bv.w);
            *(ushort4*)(Kt + ((size_t)b*N_ + n)*C_ + (ob - C_) + 4*hi) = o4;
        }
    }
    // V: 4 o-tiles per wave. A=h [pix][c], B=W' -> D[pix][o]
    #pragma unroll
    for (int ov = 0; ov < 4; ++ov) {
        int o16 = (h2*4 + ov) * 16;
        f32x4 acc = (f32x4){0.f, 0.f, 0.f, 0.f};
        #pragma unroll
        for (int ch = 0; ch < 4; ++ch) {
            bf16x8 wf = ldw8(qw + (size_t)(2*C_ + o16 + lo)*C_ + 32*ch + 8*hi);
            acc = __builtin_amdgcn_mfma_f32_16x16x32_bf16(hf[ch], wf, acc, 0, 0, 0);
        }
        float bia = qb[2*C_ + o16 + lo];
        ushort4 o4;
        o4.x = f2bf(acc[0] + bia);
        o4.y = f2bf(acc[1] + bia);
        o4.z = f2bf(acc[2] + bia);
        o4.w = f2bf(acc[3] + bia);    // 4 consecutive pixels
        *(ushort4*)(Vb + ((size_t)b*C_ + o16 + lo)*N_ + n0 + 16*p2 + 4*hi) = o4;
    }
}

// ------------- 3. bf16 MFMA flash attention, 8 waves, no in-loop barriers -------------
// Block: 32 queries, 512 threads. Wave w: query half g=w>>2 (16 q), key stripe
// si=w&3 (1024 keys, 32 iters x 32 keys). Softmax state wave-private; the two
// g-halves of a stripe read identical K/V tiles -> L1 reuse. End: 4-way combine
// per half + mfma proj (pw inline->bf16) + bias + residual.
constexpr int PS = 40;    // P row stride in u16 (32 keys + 8 pad), 16B-multiple

__global__ __launch_bounds__(512, 4) void attn_kernel(const u16* __restrict__ Qt,
                                                      const u16* __restrict__ Kt,
                                                      const u16* __restrict__ Vb,
                                                      const float* __restrict__ pw,
                                                      const float* __restrict__ pb,
                                                      const float* __restrict__ x,
                                                      float* __restrict__ out) {
    int lb = blockIdx.x;
    int b  = lb & 3;                                   // XCD-swizzle: batch per XCD
    int i0 = 32 * ((lb >> 3) + ((lb & 4) ? 64 : 0));
    int t = threadIdx.x;
    int w = t >> 6, lane = t & 63, lo = lane & 15, hi = lane >> 4;
    int g  = w >> 2;        // query half
    int si = w & 3;         // key stripe

    const u16* Qb = Qt + (size_t)b*N_*C_;
    const u16* Kb = Kt + (size_t)b*N_*C_ + (size_t)si*1024*C_;
    const u16* Vv = Vb + (size_t)b*C_*N_;
    const int vc0 = si * 1024;

    __shared__ u16 Ps[8 * 16 * PS];                    // wave-private P rows
    __shared__ float aS[8][16];
    __shared__ float mW[8][16], lW[8][16], fS[8][16];
    __shared__ float Ob[32 * 132];
    u16* Pw = Ps + w * 16 * PS;

    // persistent Q B-frags (query = i0 + 16g + lo)
    bf16x8 qf[4];
    #pragma unroll
    for (int ch = 0; ch < 4; ++ch)
        qf[ch] = *(const bf16x8*)(Qb + (size_t)(i0 + 16*g + lo)*C_ + 32*ch + 8*hi);

    f32x4 acc[8];
    #pragma unroll
    for (int ct = 0; ct < 8; ++ct) acc[ct] = (f32x4){0.f, 0.f, 0.f, 0.f};
    float m_old = -3e38f, l_run = 0.f;

    for (int it = 0; it < 32; ++it) {
        const u16* Kit = Kb + (size_t)(32*it)*C_;
        // ---- QK: S^T frags, keys 16kt+4hi+r, query lo ----
        f32x4 s0 = (f32x4){0.f,0.f,0.f,0.f}, s1 = (f32x4){0.f,0.f,0.f,0.f};
        #pragma unroll
        for (int ch = 0; ch < 4; ++ch) {
            bf16x8 k0 = *(const bf16x8*)(Kit + (size_t)lo*C_        + 32*ch + 8*hi);
            bf16x8 k1 = *(const bf16x8*)(Kit + (size_t)(16 + lo)*C_ + 32*ch + 8*hi);
            s0 = __builtin_amdgcn_mfma_f32_16x16x32_bf16(k0, qf[ch], s0, 0, 0, 0);
            s1 = __builtin_amdgcn_mfma_f32_16x16x32_bf16(k1, qf[ch], s1, 0, 0, 0);
        }
        // ---- wave-private online softmax (query = lo) ----
        float m = fmaxf(fmaxf(fmaxf(s0[0], s0[1]), fmaxf(s0[2], s0[3])),
                        fmaxf(fmaxf(s1[0], s1[1]), fmaxf(s1[2], s1[3])));
        m = fmaxf(m, __shfl_xor(m, 16));
        m = fmaxf(m, __shfl_xor(m, 32));
        float m_new = fmaxf(m_old, m);
        float alpha = __expf(m_old - m_new);
        m_old = m_new;
        if (lane < 16) aS[w][lo] = alpha;
        float p0 = __expf(s0[0] - m_new), p1 = __expf(s0[1] - m_new);
        float p2 = __expf(s0[2] - m_new), p3 = __expf(s0[3] - m_new);
        float p4 = __expf(s1[0] - m_new), p5 = __expf(s1[1] - m_new);
        float p6 = __expf(s1[2] - m_new), p7 = __expf(s1[3] - m_new);
        float psum = ((p0 + p1) + (p2 + p3)) + ((p4 + p5) + (p6 + p7));
        psum += __shfl_xor(psum, 16);
        psum += __shfl_xor(psum, 32);
        l_run = l_run * alpha + psum;
        // P -> wave-private LDS (bf16, indexed by key)
        uint2 pka, pkb;
        pka.x = pk2(p0, p1); pka.y = pk2(p2, p3);
        pkb.x = pk2(p4, p5); pkb.y = pk2(p6, p7);
        *(uint2*)(Pw + lo*PS +      4*hi) = pka;
        *(uint2*)(Pw + lo*PS + 16 + 4*hi) = pkb;
        // rescale accumulators (rows q = 4hi+r); same-wave LDS, no barrier
        float4 av = *(const float4*)(&aS[w][4*hi]);
        float am[4] = {av.x, av.y, av.z, av.w};
        #pragma unroll
        for (int ct = 0; ct < 8; ++ct)
            #pragma unroll
            for (int r = 0; r < 4; ++r) acc[ct][r] *= am[r];
        // ---- PV: A = P (LDS), B = V (global, just-in-time) ----
        bf16x8 pa = *(const bf16x8*)(Pw + lo*PS + 8*hi);
        #pragma unroll
        for (int ct = 0; ct < 8; ++ct) {
            bf16x8 vb = *(const bf16x8*)(Vv + (size_t)(16*ct + lo)*N_ + vc0 + 32*it + 8*hi);
            acc[ct] = __builtin_amdgcn_mfma_f32_16x16x32_bf16(pa, vb, acc[ct], 0, 0, 0);
        }
    }

    // ---------------- combine 4 stripes per query half ----------------
    if (lane < 16) { mW[w][lo] = m_old; lW[w][lo] = l_run; }
    __syncthreads();
    int gb = g * 4;
    float m0 = mW[gb][lo], m1 = mW[gb+1][lo], m2 = mW[gb+2][lo], m3 = mW[gb+3][lo];
    float mt = fmaxf(fmaxf(m0, m1), fmaxf(m2, m3));
    float lt = lW[gb][lo]*__expf(m0 - mt) + lW[gb+1][lo]*__expf(m1 - mt)
             + lW[gb+2][lo]*__expf(m2 - mt) + lW[gb+3][lo]*__expf(m3 - mt);
    float fac = __expf(m_old - mt) / lt;
    if (lane < 16) fS[w][lo] = fac;
    float4 fv = *(const float4*)(&fS[w][4*hi]);   // same-wave LDS
    float fm[4] = {fv.x, fv.y, fv.z, fv.w};
    #pragma unroll
    for (int ct = 0; ct < 8; ++ct)
        #pragma unroll
        for (int r = 0; r < 4; ++r) acc[ct][r] *= fm[r];
    // accumulate into Ob[q][c] (4 rounds; g-halves write disjoint rows)
    for (int i = 0; i < 4; ++i) {
        if (si == i) {
            #pragma unroll
            for (int ct = 0; ct < 8; ++ct)
                #pragma unroll
                for (int r = 0; r < 4; ++r) {
                    int q = 16*g + 4*hi + r, c = 16*ct + lo;
                    if (i == 0) Ob[q*132 + c]  = acc[ct][r];
                    else        Ob[q*132 + c] += acc[ct][r];
                }
        }
        __syncthreads();
    }
    // ---------------- proj + bias + residual ----------------
    // wave: A-tile = query half g, o-range = [32si, 32si+32)
    bf16x8 aa[4];
    #pragma unroll
    for (int ch = 0; ch < 4; ++ch) {
        float4 ua = *(const float4*)(Ob + (16*g + lo)*132 + 32*ch + 8*hi);
        float4 ub = *(const float4*)(Ob + (16*g + lo)*132 + 32*ch + 8*hi + 4);
        union { bf16x8 h; unsigned u[4]; } pkd;
        pkd.u[0] = pk2(ua.x, ua.y); pkd.u[1] = pk2(ua.z, ua.w);
        pkd.u[2] = pk2(ub.x, ub.y); pkd.u[3] = pk2(ub.z, ub.w);
        aa[ch] = pkd.h;
    }
    #pragma unroll
    for (int ot = 0; ot < 2; ++ot) {
        int ob = 32*si + 16*ot;
        f32x4 pr = (f32x4){0.f, 0.f, 0.f, 0.f};
        #pragma unroll
        for (int ch = 0; ch < 4; ++ch) {
            bf16x8 bw = ldw8(pw + (size_t)(ob + lo)*C_ + 32*ch + 8*hi);
            pr = __builtin_amdgcn_mfma_f32_16x16x32_bf16(aa[ch], bw, pr, 0, 0, 0);
        }
        int o = ob + lo;
        float pbv = pb[o];
        size_t base = ((size_t)(b*C_ + o))*N_ + i0 + 16*g + 4*hi;
        float4 xr = *(const float4*)(x + base);
        float4 res;
        res.x = xr.x + pr[0] + pbv;
        res.y = xr.y + pr[1] + pbv;
        res.z = xr.z + pr[2] + pbv;
        res.w = xr.w + pr[3] + pbv;
        *(float4*)(out + base) = res;
    }
}

extern "C" void kernel_launch(void* const* d_in, const int* in_sizes, int n_in,
                              void* d_out, int out_size, void* d_ws, size_t ws_size,
                              hipStream_t stream) {
    const float* x  = (const float*)d_in[0];
    const float* nw = (const float*)d_in[1];
    const float* nb = (const float*)d_in[2];
    const float* qw = (const float*)d_in[3];
    const float* qb = (const float*)d_in[4];
    const float* pw = (const float*)d_in[5];
    const float* pb = (const float*)d_in[6];
    float* out = (float*)d_out;

    // ws: [stats 256B][Qt 4MB][Kt 4MB][Vb 4MB] (bf16)
    float* stats = (float*)d_ws;
    u16* Qt = (u16*)((char*)d_ws + 256);
    u16* Kt = Qt + (size_t)B_*N_*C_;
    u16* Vb = Kt + (size_t)B_*N_*C_;

    hipMemsetAsync(stats, 0, 64 * sizeof(float), stream);
    prep_kernel<<<dim3(256), 256, 0, stream>>>(x, stats);
    qkv_kernel<<<dim3(512), 256, 0, stream>>>(x, stats, nw, nb, qw, qb, Qt, Kt, Vb);
    attn_kernel<<<dim3(512), 512, 0, stream>>>(Qt, Kt, Vb, pw, pb, x, out);
}

// Round 6
// 235.650 us; speedup vs baseline: 1.4646x; 1.4646x over previous
//
#include <hip/hip_runtime.h>

typedef float  f32x4  __attribute__((ext_vector_type(4)));
typedef short  bf16x8 __attribute__((ext_vector_type(8)));
typedef unsigned short u16;

constexpr int B_ = 4;
constexpr int C_ = 128;
constexpr int N_ = 4096;
constexpr int G_ = 8;
constexpr int CperG = 16;
constexpr float EPS_ = 1e-5f;
constexpr float SCALE_ = 0.08838834764831845f;  // 1/sqrt(C)

__device__ inline u16 f2bf(float f) {
    union { float f; unsigned u; } v; v.f = f;
    unsigned r = v.u + 0x7fffu + ((v.u >> 16) & 1u);  // RNE
    return (u16)(r >> 16);
}
__device__ inline unsigned pk2(float a, float b) {
    return (unsigned)f2bf(a) | ((unsigned)f2bf(b) << 16);
}
// load 8 consecutive fp32, pack to bf16x8 (inline weight conversion)
__device__ inline bf16x8 ldw8(const float* p) {
    float4 a = *(const float4*)p;
    float4 b = *(const float4*)(p + 4);
    union { bf16x8 h; unsigned u[4]; } r;
    r.u[0] = pk2(a.x, a.y); r.u[1] = pk2(a.z, a.w);
    r.u[2] = pk2(b.x, b.y); r.u[3] = pk2(b.z, b.w);
    return r.h;
}

// ---------------- 1. GroupNorm partial sums (no atomics, no memset) ----------------
// block = (bg, chunk): writes its partial (S,SS) to stats2[block*2 ..]. qkv sums 8.
__global__ __launch_bounds__(256) void prep_kernel(const float* __restrict__ x,
                                                   float* __restrict__ stats2) {
    __shared__ float rs[4], rss[4];
    int bg = blockIdx.x >> 3, chunk = blockIdx.x & 7;
    const float4* xp = (const float4*)(x + (size_t)bg * (CperG * N_)) + chunk * 2048;
    float s = 0.f, ss = 0.f;
    for (int i = threadIdx.x; i < 2048; i += 256) {
        float4 v = xp[i];
        s  += v.x + v.y + v.z + v.w;
        ss += v.x*v.x + v.y*v.y + v.z*v.z + v.w*v.w;
    }
    #pragma unroll
    for (int off = 32; off > 0; off >>= 1) {
        s  += __shfl_down(s, off);
        ss += __shfl_down(ss, off);
    }
    int wv = threadIdx.x >> 6, ln = threadIdx.x & 63;
    if (ln == 0) { rs[wv] = s; rss[wv] = ss; }
    __syncthreads();
    if (threadIdx.x == 0) {
        stats2[blockIdx.x*2]     = rs[0] + rs[1] + rs[2] + rs[3];
        stats2[blockIdx.x*2 + 1] = rss[0] + rss[1] + rss[2] + rss[3];
    }
}

// ---------------- 2. QKV via MFMA (fused GN) -> bf16, + q-norms, k-max-norm --------
// Qt[b][n][c]=(q+qb)*SCALE ; Kt[b][n][c]=k+qb ; Vb[b][c][n]=v+qb.
// qn2[b][n] = ||q_scaled||^2 per pixel ; kmaxI[b] = max_n ||k||^2 (float-as-int max).
constexpr int HS = 136;

__global__ __launch_bounds__(256) void qkv_kernel(const float* __restrict__ x,
                                                  const float* __restrict__ stats2,
                                                  const float* __restrict__ nw,
                                                  const float* __restrict__ nb,
                                                  const float* __restrict__ qw,
                                                  const float* __restrict__ qb,
                                                  u16* __restrict__ Qt,
                                                  u16* __restrict__ Kt,
                                                  u16* __restrict__ Vb,
                                                  float* __restrict__ qn2,
                                                  int* __restrict__ kmaxI) {
    int n0 = (blockIdx.x & 127) * 32;
    int b  = blockIdx.x >> 7;
    __shared__ u16 hs[32 * HS];
    __shared__ float gmean[8], grstd[8];
    int t = threadIdx.x;
    const float invM = 1.f / (float)(CperG * N_);
    if (t < 8) {
        const float* sp = stats2 + (size_t)(b*G_ + t)*16;
        float S = 0.f, SS = 0.f;
        #pragma unroll
        for (int k2 = 0; k2 < 8; ++k2) { S += sp[k2*2]; SS += sp[k2*2 + 1]; }
        float mean = S * invM;
        gmean[t] = mean;
        grstd[t] = rsqrtf(SS * invM - mean*mean + EPS_);
    }
    __syncthreads();
    #pragma unroll
    for (int r = 0; r < 4; ++r) {
        int idx = t + (r << 8);
        int c = idx >> 3, n4 = idx & 7;
        int g = c >> 4;
        float wgt = nw[c] * grstd[g];
        float bia = nb[c] - gmean[g] * wgt;
        float4 xv = *(const float4*)(x + ((size_t)(b*C_ + c))*N_ + n0 + n4*4);
        int base = (n4*4) * HS + c;
        hs[base         ] = f2bf(xv.x*wgt + bia);
        hs[base +     HS] = f2bf(xv.y*wgt + bia);
        hs[base + 2 * HS] = f2bf(xv.z*wgt + bia);
        hs[base + 3 * HS] = f2bf(xv.w*wgt + bia);
    }
    __syncthreads();
    int w = t >> 6, lane = t & 63, lo = lane & 15, hi = lane >> 4;
    int p2 = w >> 1, h2 = w & 1;
    bf16x8 hf[4];
    #pragma unroll
    for (int ch = 0; ch < 4; ++ch)
        hf[ch] = *(const bf16x8*)(hs + (16*p2 + lo)*HS + 32*ch + 8*hi);

    // Q (h2=0) or K (h2=1): 8 o-tiles. A=W [o][c], B=h -> D[o][pix]; accumulate norm^2.
    float nrm2 = 0.f;
    #pragma unroll
    for (int ot = 0; ot < 8; ++ot) {
        int ob = (h2*8 + ot) * 16;
        f32x4 acc = (f32x4){0.f, 0.f, 0.f, 0.f};
        #pragma unroll
        for (int ch = 0; ch < 4; ++ch) {
            bf16x8 wf = ldw8(qw + (size_t)(ob + lo)*C_ + 32*ch + 8*hi);
            acc = __builtin_amdgcn_mfma_f32_16x16x32_bf16(wf, hf[ch], acc, 0, 0, 0);
        }
        float4 bv = *(const float4*)(qb + ob + 4*hi);
        int n = n0 + 16*p2 + lo;
        ushort4 o4;
        if (h2 == 0) {
            float q0 = (acc[0] + bv.x) * SCALE_;
            float q1 = (acc[1] + bv.y) * SCALE_;
            float q2 = (acc[2] + bv.z) * SCALE_;
            float q3 = (acc[3] + bv.w) * SCALE_;
            nrm2 += (q0*q0 + q1*q1) + (q2*q2 + q3*q3);
            o4.x = f2bf(q0); o4.y = f2bf(q1); o4.z = f2bf(q2); o4.w = f2bf(q3);
            *(ushort4*)(Qt + ((size_t)b*N_ + n)*C_ + ob + 4*hi) = o4;
        } else {
            float k0 = acc[0] + bv.x, k1 = acc[1] + bv.y;
            float k2 = acc[2] + bv.z, k3 = acc[3] + bv.w;
            nrm2 += (k0*k0 + k1*k1) + (k2*k2 + k3*k3);
            o4.x = f2bf(k0); o4.y = f2bf(k1); o4.z = f2bf(k2); o4.w = f2bf(k3);
            *(ushort4*)(Kt + ((size_t)b*N_ + n)*C_ + (ob - C_) + 4*hi) = o4;
        }
    }
    // reduce norm^2 over the hi channel-groups -> per-pixel value
    nrm2 += __shfl_xor(nrm2, 16);
    nrm2 += __shfl_xor(nrm2, 32);
    if (h2 == 0) {
        if (lane < 16) qn2[(size_t)b*N_ + n0 + 16*p2 + lo] = nrm2;
    } else {
        #pragma unroll
        for (int off = 1; off < 16; off <<= 1)
            nrm2 = fmaxf(nrm2, __shfl_xor(nrm2, off));
        if (lane == 0) atomicMax(&kmaxI[b], __float_as_int(nrm2));  // >=0, int-order ok
    }
    // V: 4 o-tiles per wave. A=h [pix][c], B=W' -> D[pix][o]
    #pragma unroll
    for (int ov = 0; ov < 4; ++ov) {
        int o16 = (h2*4 + ov) * 16;
        f32x4 acc = (f32x4){0.f, 0.f, 0.f, 0.f};
        #pragma unroll
        for (int ch = 0; ch < 4; ++ch) {
            bf16x8 wf = ldw8(qw + (size_t)(2*C_ + o16 + lo)*C_ + 32*ch + 8*hi);
            acc = __builtin_amdgcn_mfma_f32_16x16x32_bf16(hf[ch], wf, acc, 0, 0, 0);
        }
        float bia = qb[2*C_ + o16 + lo];
        ushort4 o4;
        o4.x = f2bf(acc[0] + bia);
        o4.y = f2bf(acc[1] + bia);
        o4.z = f2bf(acc[2] + bia);
        o4.w = f2bf(acc[3] + bia);
        *(ushort4*)(Vb + ((size_t)b*C_ + o16 + lo)*N_ + n0 + 16*p2 + 4*hi) = o4;
    }
}

// ------------- 3. Bound-softmax MFMA flash attention (no in-loop reductions) -------------
// Block: 32 queries, 4 waves = 4 key stripes (1024 keys, 32 iters). Per query a
// precomputed bound m_q >= rowmax(S) replaces the online max: the loop has NO
// shfl, NO alpha rescale, NO l merge. Stripe combine = plain adds. K prefetched
// one iter ahead; V loaded at iter top, consumed at iter end.
constexpr int PS = 40;    // P row stride in u16

__global__ __launch_bounds__(256, 2) void attn_kernel(const u16* __restrict__ Qt,
                                                      const u16* __restrict__ Kt,
                                                      const u16* __restrict__ Vv_,
                                                      const float* __restrict__ qn2,
                                                      const int* __restrict__ kmaxI,
                                                      const float* __restrict__ pw,
                                                      const float* __restrict__ pb,
                                                      const float* __restrict__ x,
                                                      float* __restrict__ out) {
    int lb = blockIdx.x;
    int b  = lb & 3;                                   // XCD-swizzle: batch per XCD
    int i0 = 32 * ((lb >> 3) + ((lb & 4) ? 64 : 0));
    int t = threadIdx.x;
    int w = t >> 6, lane = t & 63, lo = lane & 15, hi = lane >> 4;

    const u16* Qb = Qt  + (size_t)b*N_*C_;
    const u16* Kw = Kt  + (size_t)b*N_*C_ + (size_t)(1024*w)*C_;
    const u16* Vv = Vv_ + (size_t)b*C_*N_;
    const int vc0 = 1024 * w;

    __shared__ u16 Ps[4 * 32 * PS];                    // wave-private P tiles (10 KB)
    __shared__ float lW[4][32];
    __shared__ float Ob[32 * 132];                     // combined O (16.9 KB)
    u16* Pw = Ps + w * 32 * PS;

    // per-query softmax bound: m_q = ||q_hat|| * max||k_hat|| * margin
    float kmax = sqrtf(__int_as_float(kmaxI[b]));
    float mq0 = sqrtf(qn2[(size_t)b*N_ + i0 + lo])      * kmax * 1.02f + 1e-6f;
    float mq1 = sqrtf(qn2[(size_t)b*N_ + i0 + 16 + lo]) * kmax * 1.02f + 1e-6f;

    // persistent Q B-frags (queries 16qt+lo)
    bf16x8 qf[2][4];
    #pragma unroll
    for (int qt = 0; qt < 2; ++qt)
        #pragma unroll
        for (int ch = 0; ch < 4; ++ch)
            qf[qt][ch] = *(const bf16x8*)(Qb + (size_t)(i0 + 16*qt + lo)*C_ + 32*ch + 8*hi);

    f32x4 acc[2][8];
    #pragma unroll
    for (int qt = 0; qt < 2; ++qt)
        #pragma unroll
        for (int ct = 0; ct < 8; ++ct) acc[qt][ct] = (f32x4){0.f, 0.f, 0.f, 0.f};
    float psum0 = 0.f, psum1 = 0.f;

    // prime K for iter 0
    bf16x8 kf[2][4], kn[2][4];
    #pragma unroll
    for (int kt = 0; kt < 2; ++kt)
        #pragma unroll
        for (int ch = 0; ch < 4; ++ch)
            kf[kt][ch] = *(const bf16x8*)(Kw + (size_t)(16*kt + lo)*C_ + 32*ch + 8*hi);

    for (int it = 0; it < 32; ++it) {
        int cur = 32 * it;
        int nx  = ((it + 1) & 31) * 32;
        // V for this iter (consumed at iter end -> latency covered by QK+softmax)
        bf16x8 vbr[8];
        #pragma unroll
        for (int ct = 0; ct < 8; ++ct)
            vbr[ct] = *(const bf16x8*)(Vv + (size_t)(16*ct + lo)*N_ + vc0 + cur + 8*hi);
        // ---- QK: S^T frags (row=key 16kt+4hi+r, col=query 16qt+lo) ----
        f32x4 s00 = (f32x4){0.f,0.f,0.f,0.f}, s01 = s00, s10 = s00, s11 = s00;
        #pragma unroll
        for (int ch = 0; ch < 4; ++ch) {
            s00 = __builtin_amdgcn_mfma_f32_16x16x32_bf16(kf[0][ch], qf[0][ch], s00, 0, 0, 0);
            s01 = __builtin_amdgcn_mfma_f32_16x16x32_bf16(kf[0][ch], qf[1][ch], s01, 0, 0, 0);
            s10 = __builtin_amdgcn_mfma_f32_16x16x32_bf16(kf[1][ch], qf[0][ch], s10, 0, 0, 0);
            s11 = __builtin_amdgcn_mfma_f32_16x16x32_bf16(kf[1][ch], qf[1][ch], s11, 0, 0, 0);
        }
        // prefetch next iter's K (wrap on last iter: redundant but in-bounds)
        #pragma unroll
        for (int kt = 0; kt < 2; ++kt)
            #pragma unroll
            for (int ch = 0; ch < 4; ++ch)
                kn[kt][ch] = *(const bf16x8*)(Kw + (size_t)(nx + 16*kt + lo)*C_ + 32*ch + 8*hi);
        // ---- p = exp(S - m_q): no max, no rescale, no cross-lane ops ----
        {
            float p0 = __expf(s00[0]-mq0), p1 = __expf(s00[1]-mq0);
            float p2 = __expf(s00[2]-mq0), p3 = __expf(s00[3]-mq0);
            psum0 += (p0+p1)+(p2+p3);
            uint2 pk; pk.x = pk2(p0,p1); pk.y = pk2(p2,p3);
            *(uint2*)(Pw + lo*PS + 4*hi) = pk;
        }
        {
            float p0 = __expf(s10[0]-mq0), p1 = __expf(s10[1]-mq0);
            float p2 = __expf(s10[2]-mq0), p3 = __expf(s10[3]-mq0);
            psum0 += (p0+p1)+(p2+p3);
            uint2 pk; pk.x = pk2(p0,p1); pk.y = pk2(p2,p3);
            *(uint2*)(Pw + lo*PS + 16 + 4*hi) = pk;
        }
        {
            float p0 = __expf(s01[0]-mq1), p1 = __expf(s01[1]-mq1);
            float p2 = __expf(s01[2]-mq1), p3 = __expf(s01[3]-mq1);
            psum1 += (p0+p1)+(p2+p3);
            uint2 pk; pk.x = pk2(p0,p1); pk.y = pk2(p2,p3);
            *(uint2*)(Pw + (16+lo)*PS + 4*hi) = pk;
        }
        {
            float p0 = __expf(s11[0]-mq1), p1 = __expf(s11[1]-mq1);
            float p2 = __expf(s11[2]-mq1), p3 = __expf(s11[3]-mq1);
            psum1 += (p0+p1)+(p2+p3);
            uint2 pk; pk.x = pk2(p0,p1); pk.y = pk2(p2,p3);
            *(uint2*)(Pw + (16+lo)*PS + 16 + 4*hi) = pk;
        }
        // ---- PV: A = P (wave-private LDS round-trip), B = V ----
        bf16x8 pa0 = *(const bf16x8*)(Pw + lo*PS + 8*hi);
        bf16x8 pa1 = *(const bf16x8*)(Pw + (16 + lo)*PS + 8*hi);
        #pragma unroll
        for (int ct = 0; ct < 8; ++ct) {
            acc[0][ct] = __builtin_amdgcn_mfma_f32_16x16x32_bf16(pa0, vbr[ct], acc[0][ct], 0, 0, 0);
            acc[1][ct] = __builtin_amdgcn_mfma_f32_16x16x32_bf16(pa1, vbr[ct], acc[1][ct], 0, 0, 0);
        }
        // rotate K buffers
        #pragma unroll
        for (int kt = 0; kt < 2; ++kt)
            #pragma unroll
            for (int ch = 0; ch < 4; ++ch) kf[kt][ch] = kn[kt][ch];
    }

    // ---------------- stripe combine: plain adds (shared m_q!) ----------------
    psum0 += __shfl_xor(psum0, 16); psum0 += __shfl_xor(psum0, 32);
    psum1 += __shfl_xor(psum1, 16); psum1 += __shfl_xor(psum1, 32);
    if (lane < 16) { lW[w][lo] = psum0; lW[w][16 + lo] = psum1; }
    __syncthreads();
    for (int i = 0; i < 4; ++i) {
        if (w == i) {
            #pragma unroll
            for (int qt = 0; qt < 2; ++qt)
                #pragma unroll
                for (int ct = 0; ct < 8; ++ct)
                    #pragma unroll
                    for (int r = 0; r < 4; ++r) {
                        int q = 16*qt + 4*hi + r, c = 16*ct + lo;
                        if (i == 0) Ob[q*132 + c]  = acc[qt][ct][r];
                        else        Ob[q*132 + c] += acc[qt][ct][r];
                    }
        }
        __syncthreads();
    }
    // ---------------- proj + bias + residual ----------------
    float linv[2];
    #pragma unroll
    for (int qt = 0; qt < 2; ++qt) {
        int q = 16*qt + lo;
        linv[qt] = 1.f / (lW[0][q] + lW[1][q] + lW[2][q] + lW[3][q]);
    }
    bf16x8 aa[2][4];
    #pragma unroll
    for (int qt = 0; qt < 2; ++qt)
        #pragma unroll
        for (int ch = 0; ch < 4; ++ch) {
            float4 ua = *(const float4*)(Ob + (16*qt + lo)*132 + 32*ch + 8*hi);
            float4 ub = *(const float4*)(Ob + (16*qt + lo)*132 + 32*ch + 8*hi + 4);
            union { bf16x8 h; unsigned u[4]; } pkd;
            pkd.u[0] = pk2(ua.x*linv[qt], ua.y*linv[qt]);
            pkd.u[1] = pk2(ua.z*linv[qt], ua.w*linv[qt]);
            pkd.u[2] = pk2(ub.x*linv[qt], ub.y*linv[qt]);
            pkd.u[3] = pk2(ub.z*linv[qt], ub.w*linv[qt]);
            aa[qt][ch] = pkd.h;
        }
    #pragma unroll
    for (int ot = 0; ot < 2; ++ot) {
        int ob = 32*w + 16*ot;
        f32x4 pr0 = (f32x4){0.f,0.f,0.f,0.f}, pr1 = pr0;
        #pragma unroll
        for (int ch = 0; ch < 4; ++ch) {
            bf16x8 bw = ldw8(pw + (size_t)(ob + lo)*C_ + 32*ch + 8*hi);
            pr0 = __builtin_amdgcn_mfma_f32_16x16x32_bf16(aa[0][ch], bw, pr0, 0, 0, 0);
            pr1 = __builtin_amdgcn_mfma_f32_16x16x32_bf16(aa[1][ch], bw, pr1, 0, 0, 0);
        }
        int o = ob + lo;
        float pbv = pb[o];
        #pragma unroll
        for (int qt = 0; qt < 2; ++qt) {
            f32x4 pr = qt ? pr1 : pr0;
            size_t base = ((size_t)(b*C_ + o))*N_ + i0 + 16*qt + 4*hi;
            float4 xr = *(const float4*)(x + base);
            float4 res;
            res.x = xr.x + pr[0] + pbv;
            res.y = xr.y + pr[1] + pbv;
            res.z = xr.z + pr[2] + pbv;
            res.w = xr.w + pr[3] + pbv;
            *(float4*)(out + base) = res;
        }
    }
}

extern "C" void kernel_launch(void* const* d_in, const int* in_sizes, int n_in,
                              void* d_out, int out_size, void* d_ws, size_t ws_size,
                              hipStream_t stream) {
    const float* x  = (const float*)d_in[0];
    const float* nw = (const float*)d_in[1];
    const float* nb = (const float*)d_in[2];
    const float* qw = (const float*)d_in[3];
    const float* qb = (const float*)d_in[4];
    const float* pw = (const float*)d_in[5];
    const float* pb = (const float*)d_in[6];
    float* out = (float*)d_out;

    // ws: [stats2 2KB][qn2 64KB][kmaxI 16B pad 256B][Qt 4MB][Kt 4MB][Vb 4MB]
    float* stats2 = (float*)d_ws;
    float* qn2    = stats2 + 512;
    int*   kmaxI  = (int*)(qn2 + (size_t)B_*N_);       // 0xAA poison = negative int: atomicMax-safe
    u16*   Qt     = (u16*)((char*)d_ws + 2048 + 65536 + 256);
    u16*   Kt     = Qt + (size_t)B_*N_*C_;
    u16*   Vb     = Kt + (size_t)B_*N_*C_;

    prep_kernel<<<dim3(256), 256, 0, stream>>>(x, stats2);
    qkv_kernel<<<dim3(512), 256, 0, stream>>>(x, stats2, nw, nb, qw, qb, Qt, Kt, Vb, qn2, kmaxI);
    attn_kernel<<<dim3(512), 256, 0, stream>>>(Qt, Kt, Vb, qn2, kmaxI, pw, pb, x, out);
}

// Round 7
// 180.931 us; speedup vs baseline: 1.9075x; 1.3024x over previous
//
#include <hip/hip_runtime.h>

typedef float  f32x4  __attribute__((ext_vector_type(4)));
typedef short  bf16x8 __attribute__((ext_vector_type(8)));
typedef unsigned short u16;

constexpr int B_ = 4;
constexpr int C_ = 128;
constexpr int N_ = 4096;
constexpr int G_ = 8;
constexpr int CperG = 16;
constexpr float EPS_ = 1e-5f;
constexpr float SCALE_ = 0.08838834764831845f;  // 1/sqrt(C)

__device__ inline u16 f2bf(float f) {
    union { float f; unsigned u; } v; v.f = f;
    unsigned r = v.u + 0x7fffu + ((v.u >> 16) & 1u);  // RNE
    return (u16)(r >> 16);
}
__device__ inline unsigned pk2(float a, float b) {
    return (unsigned)f2bf(a) | ((unsigned)f2bf(b) << 16);
}
// async global->LDS, 16B per lane. LDS dest = wave-uniform base + lane*16.
__device__ inline void gload16(const u16* g, u16* l) {
    __builtin_amdgcn_global_load_lds(
        (const __attribute__((address_space(1))) void*)g,
        (__attribute__((address_space(3))) void*)l, 16, 0, 0);
}

// ---------------- 1. prep: GN partials + weight bf16 conversion ----------------
__global__ __launch_bounds__(256) void prep_kernel(const float* __restrict__ x,
                                                   const float* __restrict__ qw,
                                                   const float* __restrict__ pw,
                                                   float* __restrict__ stats2,
                                                   u16* __restrict__ qwbf,
                                                   u16* __restrict__ pwbf) {
    int blk = blockIdx.x;
    if (blk < 256) {
        __shared__ float rs[4], rss[4];
        int bg = blk >> 3, chunk = blk & 7;
        const float4* xp = (const float4*)(x + (size_t)bg * (CperG * N_)) + chunk * 2048;
        float s = 0.f, ss = 0.f;
        for (int i = threadIdx.x; i < 2048; i += 256) {
            float4 v = xp[i];
            s  += v.x + v.y + v.z + v.w;
            ss += v.x*v.x + v.y*v.y + v.z*v.z + v.w*v.w;
        }
        #pragma unroll
        for (int off = 32; off > 0; off >>= 1) {
            s  += __shfl_down(s, off);
            ss += __shfl_down(ss, off);
        }
        int wv = threadIdx.x >> 6, ln = threadIdx.x & 63;
        if (ln == 0) { rs[wv] = s; rss[wv] = ss; }
        __syncthreads();
        if (threadIdx.x == 0) {
            stats2[blk*2]     = rs[0] + rs[1] + rs[2] + rs[3];
            stats2[blk*2 + 1] = rss[0] + rss[1] + rss[2] + rss[3];
        }
    } else {
        int fidx = ((blk - 256) * 256 + threadIdx.x) * 4;   // 64 blocks * 1024 f32
        float4 v;
        u16* dst;
        if (fidx < 3*C_*C_) { v = *(const float4*)(qw + fidx); dst = qwbf + fidx; }
        else { int j = fidx - 3*C_*C_; v = *(const float4*)(pw + j); dst = pwbf + j; }
        ushort4 o;
        o.x = f2bf(v.x); o.y = f2bf(v.y); o.z = f2bf(v.z); o.w = f2bf(v.w);
        *(ushort4*)dst = o;
    }
}

// ---------------- 2. QKV via MFMA: h AND W staged in LDS (no global frag loads) ----
// Block: 64-pixel tile, 4 waves (16 px each). Loops 6 o-chunks of 64, staging
// the W chunk (padded stride) each time. Also emits q-norms / k-max-norm for
// the bound softmax.
constexpr int HS = 136;   // padded row stride (u16) for hs and Wl

__global__ __launch_bounds__(256, 2) void qkv_kernel(const float* __restrict__ x,
                                                     const float* __restrict__ stats2,
                                                     const float* __restrict__ nw,
                                                     const float* __restrict__ nb,
                                                     const u16* __restrict__ qwbf,
                                                     const float* __restrict__ qb,
                                                     u16* __restrict__ Qt,
                                                     u16* __restrict__ Kt,
                                                     u16* __restrict__ Vb,
                                                     float* __restrict__ qn2,
                                                     int* __restrict__ kmaxI) {
    int n0 = (blockIdx.x & 63) * 64;
    int b  = blockIdx.x >> 6;
    __shared__ u16 hs[64 * HS];     // 17.4 KB
    __shared__ u16 Wl[64 * HS];     // 17.4 KB (one 64-row weight chunk)
    __shared__ float gmean[8], grstd[8];
    int t = threadIdx.x;
    const float invM = 1.f / (float)(CperG * N_);
    if (t < 8) {
        const float* sp = stats2 + (size_t)(b*G_ + t)*16;
        float S = 0.f, SS = 0.f;
        #pragma unroll
        for (int k2 = 0; k2 < 8; ++k2) { S += sp[k2*2]; SS += sp[k2*2 + 1]; }
        float mean = S * invM;
        gmean[t] = mean;
        grstd[t] = rsqrtf(SS * invM - mean*mean + EPS_);
    }
    __syncthreads();
    // stage h: 64 px x 128 c, [px][c] padded
    #pragma unroll
    for (int r = 0; r < 8; ++r) {
        int idx = t + (r << 8);
        int c = idx >> 4, n4 = idx & 15;     // c 0..127, n4: 16 groups of 4 px
        int g = c >> 4;
        float wgt = nw[c] * grstd[g];
        float bia = nb[c] - gmean[g] * wgt;
        float4 xv = *(const float4*)(x + ((size_t)(b*C_ + c))*N_ + n0 + n4*4);
        int base = (n4*4) * HS + c;
        hs[base         ] = f2bf(xv.x*wgt + bia);
        hs[base +     HS] = f2bf(xv.y*wgt + bia);
        hs[base + 2 * HS] = f2bf(xv.z*wgt + bia);
        hs[base + 3 * HS] = f2bf(xv.w*wgt + bia);
    }
    __syncthreads();
    int w = t >> 6, lane = t & 63, lo = lane & 15, hi = lane >> 4;
    bf16x8 hf[4];
    #pragma unroll
    for (int ch = 0; ch < 4; ++ch)
        hf[ch] = *(const bf16x8*)(hs + (16*w + lo)*HS + 32*ch + 8*hi);

    float nq = 0.f, nk = 0.f;
    for (int ck = 0; ck < 6; ++ck) {
        // stage W chunk rows [64ck, 64ck+64) coalesced, padded stride
        {
            int r = t >> 2, p = t & 3;        // row, 32-u16 part
            const u16* src = qwbf + (size_t)(ck*64 + r)*C_ + p*32;
            u16* dst = Wl + r*HS + p*32;
            #pragma unroll
            for (int k2 = 0; k2 < 4; ++k2)
                *(uint4*)(dst + 8*k2) = *(const uint4*)(src + 8*k2);
        }
        __syncthreads();
        #pragma unroll
        for (int ot = 0; ot < 4; ++ot) {
            int o16 = ck*64 + ot*16;          // global o base (0..383)
            bf16x8 wf[4];
            #pragma unroll
            for (int ch = 0; ch < 4; ++ch)
                wf[ch] = *(const bf16x8*)(Wl + (ot*16 + lo)*HS + 32*ch + 8*hi);
            if (o16 < 2*C_) {
                // Q/K: A=W (m=o), B=h (n=px) -> D[o][px]
                f32x4 acc = (f32x4){0.f, 0.f, 0.f, 0.f};
                #pragma unroll
                for (int ch = 0; ch < 4; ++ch)
                    acc = __builtin_amdgcn_mfma_f32_16x16x32_bf16(wf[ch], hf[ch], acc, 0, 0, 0);
                float4 bv = *(const float4*)(qb + o16 + 4*hi);
                int n = n0 + 16*w + lo;
                ushort4 o4;
                if (o16 < C_) {
                    float q0 = (acc[0] + bv.x) * SCALE_;
                    float q1 = (acc[1] + bv.y) * SCALE_;
                    float q2 = (acc[2] + bv.z) * SCALE_;
                    float q3 = (acc[3] + bv.w) * SCALE_;
                    nq += (q0*q0 + q1*q1) + (q2*q2 + q3*q3);
                    o4.x = f2bf(q0); o4.y = f2bf(q1); o4.z = f2bf(q2); o4.w = f2bf(q3);
                    *(ushort4*)(Qt + ((size_t)b*N_ + n)*C_ + o16 + 4*hi) = o4;
                } else {
                    float k0 = acc[0] + bv.x, k1 = acc[1] + bv.y;
                    float k2 = acc[2] + bv.z, k3 = acc[3] + bv.w;
                    nk += (k0*k0 + k1*k1) + (k2*k2 + k3*k3);
                    o4.x = f2bf(k0); o4.y = f2bf(k1); o4.z = f2bf(k2); o4.w = f2bf(k3);
                    *(ushort4*)(Kt + ((size_t)b*N_ + n)*C_ + (o16 - C_) + 4*hi) = o4;
                }
            } else {
                // V: A=h (m=px), B=W (n=o) -> D[px][o]
                f32x4 acc = (f32x4){0.f, 0.f, 0.f, 0.f};
                #pragma unroll
                for (int ch = 0; ch < 4; ++ch)
                    acc = __builtin_amdgcn_mfma_f32_16x16x32_bf16(hf[ch], wf[ch], acc, 0, 0, 0);
                float bia = qb[o16 + lo];
                ushort4 o4;
                o4.x = f2bf(acc[0] + bia);
                o4.y = f2bf(acc[1] + bia);
                o4.z = f2bf(acc[2] + bia);
                o4.w = f2bf(acc[3] + bia);    // 4 consecutive px
                *(ushort4*)(Vb + ((size_t)b*C_ + (o16 - 2*C_) + lo)*N_ + n0 + 16*w + 4*hi) = o4;
            }
        }
        __syncthreads();    // all frag reads done before next chunk overwrites Wl
    }
    // per-pixel norms (px = n0+16w+lo): reduce over hi groups
    nq += __shfl_xor(nq, 16); nq += __shfl_xor(nq, 32);
    nk += __shfl_xor(nk, 16); nk += __shfl_xor(nk, 32);
    if (lane < 16) qn2[(size_t)b*N_ + n0 + 16*w + lo] = nq;
    #pragma unroll
    for (int off = 1; off < 16; off <<= 1)
        nk = fmaxf(nk, __shfl_xor(nk, off));
    if (lane == 0) atomicMax(&kmaxI[b], __float_as_int(nk));  // poison is negative: safe
}

// ------------- 3. LDS-staged MFMA flash attention (bound softmax) -------------
// Block: 32 queries, 4 waves = (qg: 16-q half) x (ks: 32-key half of the 64-key
// tile). K/V staged per tile via global_load_lds (XOR-swizzled global chunk per
// lane -> conflict-free LDS frag reads without padding). 2 barriers/iter,
// single-buffered; 2 blocks/CU give cross-block overlap (m97 structure).
constexpr int PS = 40;    // P row stride in u16

__global__ __launch_bounds__(256, 2) void attn_kernel(const u16* __restrict__ Qt,
                                                      const u16* __restrict__ Kt,
                                                      const u16* __restrict__ Vb,
                                                      const float* __restrict__ qn2,
                                                      const int* __restrict__ kmaxI,
                                                      const u16* __restrict__ pwbf,
                                                      const float* __restrict__ pb,
                                                      const float* __restrict__ x,
                                                      float* __restrict__ out) {
    int lb = blockIdx.x;
    int b  = lb & 3;                       // XCD-swizzle: one batch per XCD
    int i0 = 32 * (lb >> 2);
    int t = threadIdx.x;
    int w = t >> 6, lane = t & 63, lo = lane & 15, hi = lane >> 4;
    int qg = w >> 1, ks = w & 1;

    const u16* Qb = Qt + (size_t)b*N_*C_;
    const u16* Kb = Kt + (size_t)b*N_*C_;
    const u16* Vv = Vb + (size_t)b*C_*N_;

    __shared__ __align__(16) u16 KV[16384];      // Kl[64 keys][128c] | Vl[128c][64k]
    __shared__ __align__(16) u16 Ps[4 * 16 * PS];
    __shared__ float lW[4][16];
    u16* Kl = KV;
    u16* Vl = KV + 8192;
    u16* Pw = Ps + w * 16 * PS;
    float* Ob = (float*)KV;                      // epilogue overlay (4224 f32)

    float kmax = sqrtf(__int_as_float(kmaxI[b]));
    float mq = sqrtf(qn2[(size_t)b*N_ + i0 + 16*qg + lo]) * kmax * 1.02f + 1e-6f;

    bf16x8 qf[4];
    #pragma unroll
    for (int ch = 0; ch < 4; ++ch)
        qf[ch] = *(const bf16x8*)(Qb + (size_t)(i0 + 16*qg + lo)*C_ + 32*ch + 8*hi);

    f32x4 acc[8];
    #pragma unroll
    for (int ct = 0; ct < 8; ++ct) acc[ct] = (f32x4){0.f, 0.f, 0.f, 0.f};
    float psum = 0.f;

    int srow  = lane >> 4;     // staging helper rows
    int schnk = lane & 15;
    int vrow  = lane >> 3;
    int vchnk = lane & 7;

    for (int it = 0; it < 64; ++it) {
        int tile0 = it * 64;
        // ---- cooperative stage: waves 0,1 -> K (32 rows each); 2,3 -> V ----
        if (w < 2) {
            #pragma unroll
            for (int j = 0; j < 8; ++j) {
                int k0 = 32*w + 4*j;
                int r  = k0 + srow;                      // key row 0..63
                const u16* g = Kb + (size_t)(tile0 + r)*C_ + (schnk ^ (r & 15))*8;
                gload16(g, Kl + k0*128);
            }
        } else {
            #pragma unroll
            for (int j = 0; j < 8; ++j) {
                int c0 = 64*(w - 2) + 8*j;
                int ch = c0 + vrow;                      // channel row 0..127
                const u16* g = Vv + (size_t)ch*N_ + tile0 + (vchnk ^ (ch & 7))*8;
                gload16(g, Vl + c0*64);
            }
        }
        __syncthreads();
        // ---- QK: S^T frags (keys 16kt+4hi+r of this ks-half, query lo) ----
        f32x4 s0 = (f32x4){0.f,0.f,0.f,0.f}, s1 = s0;
        #pragma unroll
        for (int ch = 0; ch < 4; ++ch) {
            int kk0 = 32*ks + lo, kk1 = kk0 + 16;
            bf16x8 k0f = *(const bf16x8*)(Kl + kk0*128 + (((4*ch + hi) ^ lo))*8);
            bf16x8 k1f = *(const bf16x8*)(Kl + kk1*128 + (((4*ch + hi) ^ lo))*8);
            s0 = __builtin_amdgcn_mfma_f32_16x16x32_bf16(k0f, qf[ch], s0, 0, 0, 0);
            s1 = __builtin_amdgcn_mfma_f32_16x16x32_bf16(k1f, qf[ch], s1, 0, 0, 0);
        }
        // ---- bound softmax: p = exp(S - m_q), no reductions ----
        {
            float p0 = __expf(s0[0]-mq), p1 = __expf(s0[1]-mq);
            float p2 = __expf(s0[2]-mq), p3 = __expf(s0[3]-mq);
            psum += (p0+p1)+(p2+p3);
            uint2 pk; pk.x = pk2(p0,p1); pk.y = pk2(p2,p3);
            *(uint2*)(Pw + lo*PS + 4*hi) = pk;
        }
        {
            float p0 = __expf(s1[0]-mq), p1 = __expf(s1[1]-mq);
            float p2 = __expf(s1[2]-mq), p3 = __expf(s1[3]-mq);
            psum += (p0+p1)+(p2+p3);
            uint2 pk; pk.x = pk2(p0,p1); pk.y = pk2(p2,p3);
            *(uint2*)(Pw + lo*PS + 16 + 4*hi) = pk;
        }
        // ---- PV: A = P (wave-private), B = V frags from LDS ----
        bf16x8 pa = *(const bf16x8*)(Pw + lo*PS + 8*hi);
        #pragma unroll
        for (int ct = 0; ct < 8; ++ct) {
            int cc = 16*ct + lo;
            bf16x8 vf = *(const bf16x8*)(Vl + cc*64 + (((4*ks + hi) ^ (cc & 7)))*8);
            acc[ct] = __builtin_amdgcn_mfma_f32_16x16x32_bf16(pa, vf, acc[ct], 0, 0, 0);
        }
        __syncthreads();   // all reads done before next tile overwrites KV
    }

    // ---------------- combine ks-halves (plain adds: shared m_q) ----------------
    psum += __shfl_xor(psum, 16);
    psum += __shfl_xor(psum, 32);
    if (lane < 16) lW[w][lo] = psum;
    for (int i = 0; i < 2; ++i) {
        if (ks == i) {
            #pragma unroll
            for (int ct = 0; ct < 8; ++ct)
                #pragma unroll
                for (int r = 0; r < 4; ++r) {
                    int q = 16*qg + 4*hi + r, c = 16*ct + lo;
                    if (i == 0) Ob[q*132 + c]  = acc[ct][r];
                    else        Ob[q*132 + c] += acc[ct][r];
                }
        }
        __syncthreads();
    }
    // ---------------- proj + bias + residual ----------------
    float linv = 1.f / (lW[2*qg][lo] + lW[2*qg + 1][lo]);   // query 16qg+lo
    bf16x8 aa[4];
    #pragma unroll
    for (int ch = 0; ch < 4; ++ch) {
        float4 ua = *(const float4*)(Ob + (16*qg + lo)*132 + 32*ch + 8*hi);
        float4 ub = *(const float4*)(Ob + (16*qg + lo)*132 + 32*ch + 8*hi + 4);
        union { bf16x8 h; unsigned u[4]; } pkd;
        pkd.u[0] = pk2(ua.x*linv, ua.y*linv);
        pkd.u[1] = pk2(ua.z*linv, ua.w*linv);
        pkd.u[2] = pk2(ub.x*linv, ub.y*linv);
        pkd.u[3] = pk2(ub.z*linv, ub.w*linv);
        aa[ch] = pkd.h;
    }
    #pragma unroll
    for (int ot = 0; ot < 4; ++ot) {
        int ob = 64*ks + 16*ot;
        f32x4 pr = (f32x4){0.f, 0.f, 0.f, 0.f};
        #pragma unroll
        for (int ch = 0; ch < 4; ++ch) {
            bf16x8 bw = *(const bf16x8*)(pwbf + (size_t)(ob + lo)*C_ + 32*ch + 8*hi);
            pr = __builtin_amdgcn_mfma_f32_16x16x32_bf16(aa[ch], bw, pr, 0, 0, 0);
        }
        int o = ob + lo;
        float pbv = pb[o];
        size_t base = ((size_t)(b*C_ + o))*N_ + i0 + 16*qg + 4*hi;
        float4 xr = *(const float4*)(x + base);
        float4 res;
        res.x = xr.x + pr[0] + pbv;
        res.y = xr.y + pr[1] + pbv;
        res.z = xr.z + pr[2] + pbv;
        res.w = xr.w + pr[3] + pbv;
        *(float4*)(out + base) = res;
    }
}

extern "C" void kernel_launch(void* const* d_in, const int* in_sizes, int n_in,
                              void* d_out, int out_size, void* d_ws, size_t ws_size,
                              hipStream_t stream) {
    const float* x  = (const float*)d_in[0];
    const float* nw = (const float*)d_in[1];
    const float* nb = (const float*)d_in[2];
    const float* qw = (const float*)d_in[3];
    const float* qb = (const float*)d_in[4];
    const float* pw = (const float*)d_in[5];
    const float* pb = (const float*)d_in[6];
    float* out = (float*)d_out;

    // ws: [stats2 2KB][qn2 64KB][kmaxI 256B][qwbf 96KB][pwbf 32KB][Qt 4MB][Kt 4MB][Vb 4MB]
    char* p = (char*)d_ws;
    float* stats2 = (float*)p;                 p += 2048;
    float* qn2    = (float*)p;                 p += (size_t)B_*N_*4;
    int*   kmaxI  = (int*)p;                   p += 256;
    u16*   qwbf   = (u16*)p;                   p += (size_t)3*C_*C_*2;
    u16*   pwbf   = (u16*)p;                   p += (size_t)C_*C_*2;
    u16*   Qt     = (u16*)p;                   p += (size_t)B_*N_*C_*2;
    u16*   Kt     = (u16*)p;                   p += (size_t)B_*N_*C_*2;
    u16*   Vb     = (u16*)p;

    prep_kernel<<<dim3(320), 256, 0, stream>>>(x, qw, pw, stats2, qwbf, pwbf);
    qkv_kernel<<<dim3(256), 256, 0, stream>>>(x, stats2, nw, nb, qwbf, qb,
                                              Qt, Kt, Vb, qn2, kmaxI);
    attn_kernel<<<dim3(512), 256, 0, stream>>>(Qt, Kt, Vb, qn2, kmaxI,
                                               pwbf, pb, x, out);
}